// Round 3
// baseline (2622.131 us; speedup 1.0000x reference)
//
#include <hip/hip_runtime.h>
#include <cstdint>
#include <cstddef>

#define S 108
#define NEMIT 126
#define NCOD 16
#define T_LEN 2048
#define N_BATCH 256
#define MAXP 20   // max in-degree of column pair (2l,2l+1) is 19 (cols 52+53)

// ---- emission-structure enumeration (mirrors _emission_structure) ----
// sym codes: 0..3 = A,C,G,T ; 4 = 'N' (expands to {0,1,2,3}) ; 5 = 'X' marker
__device__ __forceinline__ int maskFor(int sym, int add4) {
  int m = (sym == 4) ? 0xF : (1 << sym);
  if (add4) m |= 0x10;           // literal kmer digit 4 ("pad") allowed
  return m;
}

// Iterates accepted kmer ids in EXACT Python product() order.
template <typename F>
__device__ __forceinline__ void enumCall(int s0, int s1, int s2, int xmust, F&& f) {
  int m0 = maskFor(s0, xmust < 2 ? 1 : 0);
  int m1 = maskFor(s1, xmust < 1 ? 1 : 0);
  int m2 = maskFor(s2, 0);
  for (int x0 = 0; x0 < 5; x0++) {
    if (!((m0 >> x0) & 1)) continue;
    for (int x1 = 0; x1 < 5; x1++) {
      if (!((m1 >> x1) & 1)) continue;
      if (x0 != 4 && x1 == 4) continue;   // 4s must be a prefix among first two
      for (int x2 = 0; x2 < 5; x2++) {
        if (!((m2 >> x2) & 1)) continue;
        f(x0 * 25 + x1 * 5 + x2);
      }
    }
  }
}

__global__ __launch_bounds__(64, 1) void hmm_scan_kernel(
    const int* __restrict__ inp, const float* __restrict__ w,
    const float* __restrict__ ek, const float* __restrict__ ik,
    float* __restrict__ out) {
  __shared__ __align__(16) float Bt_lds[NEMIT * S];  // Bt[col*S + state], 54.4 KB
  __shared__ __align__(8) float alpha_lds[128];      // pad: lanes 54..63 write junk slots
  __shared__ float pi_lds[S];
  __shared__ short arow[288], acol[288];
  __shared__ float avalS[288];
  __shared__ int s_ne, s_ncalls;
  __shared__ unsigned char cst[116], cs0[116], cs1[116], cs2[116], cxm[116], ctr[116];
  __shared__ int kOffL[116];

  const int tid = threadIdx.x;   // 64 threads = 1 wave

  // ---------- phase 0: zero Bt; serial builders on lanes 0/1/2 ----------
  for (int i = tid; i < NEMIT * S; i += 64) Bt_lds[i] = 0.f;

  if (tid == 0) {
    int c = 0;
    auto CC = [&](int st, int a, int b, int d, int xm, int tr) {
      cst[c] = (unsigned char)st; cs0[c] = (unsigned char)a; cs1[c] = (unsigned char)b;
      cs2[c] = (unsigned char)d; cxm[c] = (unsigned char)xm; ctr[c] = (unsigned char)tr; c++;
    };
    CC(0, 4, 4, 4, 0, 1);            // 'N'
    CC(1, 4, 4, 0, 0, 1);            // 'A'
    CC(2, 4, 0, 3, 0, 1);            // 'AT'
    CC(3, 0, 3, 2, 2, 0);            // 'ATG'  (non-trainable)
    CC(4, 3, 2, 4, 2, 1);            // 'ATGN'
    CC(5, 2, 4, 4, 2, 1);            // 'ATGNN'
    for (int s = 6; s <= 51; s++) CC(s, 4, 4, 4, 2, 1);
    CC(52, 4, 4, 3, 2, 1);           // 'T'
    CC(53, 4, 3, 0, 2, 1);           // 'TA'
    CC(53, 4, 3, 2, 2, 1);           // 'TG'
    CC(54, 3, 0, 0, 2, 0);           // 'TAA'
    CC(54, 3, 0, 2, 2, 0);           // 'TAG'
    CC(54, 3, 2, 0, 2, 0);           // 'TGA'
    CC(55, 4, 4, 4, 2, 1);
    for (int s = 56; s <= 106; s++) CC(s, 4, 4, 4, 2, 1);
    CC(107, 5, 5, 5, 2, 1);          // 'X' special (col 125, widx -1)
    s_ncalls = c;                    // = 111
  }
  if (tid == 1) {
    int ne = 0;
    auto AD = [&](int r, int c2, float v) {
      arow[ne] = (short)r; acol[ne] = (short)c2; avalS[ne] = v; ne++;
    };
    float w0 = w[0];
    AD(0, 0, 1.f - w0); AD(0, 1, w0); AD(1, 2, 1.f); AD(2, 3, 1.f);
    int k = 1;
    for (int i = 0; i < NCOD; i++) AD(3 + 3 * i, 4 + 3 * i, w[k + i]);
    k += NCOD;                                            // k = 17
    for (int i = 0; i < NCOD; i++) AD(4 + 3 * i, 5 + 3 * i, 1.f);
    for (int i = 0; i < NCOD; i++) AD(5 + 3 * i, 6 + 3 * i, 1.f);
    for (int i = 0; i <= NCOD; i++) AD(3 + 3 * i, 56 + 3 * i, w[k + i]);
    k += NCOD + 1;                                        // k = 34
    AD(51, 52, w[k]); k += 1;                             // k = 35
    for (int i = 0; i <= NCOD; i++) AD(56 + 3 * i, 57 + 3 * i, 1.f);
    for (int i = 0; i <= NCOD; i++) AD(57 + 3 * i, 58 + 3 * i, 1.f);
    for (int i = 0; i <= NCOD; i++) AD(58 + 3 * i, 4 + 3 * i, w[k + i]);
    for (int i = 0; i <= NCOD; i++) AD(58 + 3 * i, 56 + 3 * i, 1.f - w[k + i]);
    k += NCOD + 1;                                        // k = 52
    float wk = w[k];
    float sgnw = (wk > 0.f) ? 1.f : ((wk < 0.f) ? -1.f : 0.f);
    for (int a = 0; a < NCOD; a++)
      for (int jj = a + 1; jj <= NCOD; jj++) {
        int e = jj - a + 1;
        float sgn = (e & 1) ? sgnw : 1.f;
        AD(3 + 3 * a, 4 + 3 * jj, 1.f - sgn * powf(fabsf(wk), (float)e));
      }
    AD(52, 53, 1.f); AD(53, 54, 1.f); AD(54, 55, 1.f);
    AD(55, 55, 1.f); AD(55, 107, 1.f); AD(107, 107, 1.f);
    s_ne = ne;                                            // = 280
  }
  if (tid == 2) {
    float m = -1e30f;
    for (int i = 0; i < S; i++) m = fmaxf(m, ik[i]);
    float z = 0.f;
    for (int i = 0; i < S; i++) z += expf(ik[i] - m);
    for (int i = 0; i < S; i++) pi_lds[i] = expf(ik[i] - m) / z;
  }
  __syncthreads();

  const int ncalls = s_ncalls;
  const int ne = s_ne;

  // ---------- phase 1: per-call weight offsets; A row-softmax ----------
  for (int cc = tid; cc < ncalls; cc += 64) {
    int ko = 0;
    for (int c = 0; c < cc; c++) {
      if (ctr[c] && cs0[c] != 5) {
        int cnt = 0;
        enumCall(cs0[c], cs1[c], cs2[c], cxm[c], [&](int) { cnt++; });
        ko += cnt;
      }
    }
    kOffL[cc] = ko;
  }
  for (int s = tid; s < S; s += 64) {    // A row-softmax, in-place on avalS
    float m = -1e30f;
    for (int e = 0; e < ne; e++)
      if (arow[e] == s) m = fmaxf(m, avalS[e]);
    float z = 0.f;
    for (int e = 0; e < ne; e++)
      if (arow[e] == s) z += expf(avalS[e] - m);
    for (int e = 0; e < ne; e++)
      if (arow[e] == s) avalS[e] = expf(avalS[e] - m) / z;
  }
  __syncthreads();

  // ---------- phase 2: B row-softmax -> Bt_lds ----------
  for (int s = tid; s < S; s += 64) {
    float m = -1e30f;
    for (int c = 0; c < ncalls; c++) {
      if (cst[c] != s) continue;
      if (cs0[c] == 5) { m = fmaxf(m, 1.f); continue; }
      if (ctr[c]) {
        int ko = kOffL[c];
        enumCall(cs0[c], cs1[c], cs2[c], cxm[c], [&](int) { m = fmaxf(m, ek[ko++]); });
      } else {
        m = fmaxf(m, 1.f);
      }
    }
    float z = 0.f;
    for (int c = 0; c < ncalls; c++) {
      if (cst[c] != s) continue;
      if (cs0[c] == 5) { z += expf(1.f - m); continue; }
      if (ctr[c]) {
        int ko = kOffL[c];
        enumCall(cs0[c], cs1[c], cs2[c], cxm[c], [&](int) { z += expf(ek[ko++] - m); });
      } else {
        enumCall(cs0[c], cs1[c], cs2[c], cxm[c], [&](int) { z += expf(1.f - m); });
      }
    }
    for (int c = 0; c < ncalls; c++) {
      if (cst[c] != s) continue;
      if (cs0[c] == 5) { Bt_lds[125 * S + s] = expf(1.f - m) / z; continue; }
      if (ctr[c]) {
        int ko = kOffL[c];
        enumCall(cs0[c], cs1[c], cs2[c], cxm[c],
                 [&](int col) { Bt_lds[col * S + s] = expf(ek[ko++] - m) / z; });
      } else {
        enumCall(cs0[c], cs1[c], cs2[c], cxm[c],
                 [&](int col) { Bt_lds[col * S + s] = expf(1.f - m) / z; });
      }
    }
  }

  // ---------- phase 3: per-lane CSC of columns (2l, 2l+1), static slots ----------
  const int s0 = (tid < 54) ? 2 * tid : -1;
  const int s1 = (tid < 54) ? 2 * tid + 1 : -1;
  float gv0[MAXP], gv1[MAXP];
  int gi[MAXP];
#pragma unroll
  for (int e = 0; e < MAXP; e++) { gv0[e] = 0.f; gv1[e] = 0.f; gi[e] = 0; }
  {
    int cnt = 0;
    for (int e = 0; e < ne; e++) {
      const int c = (int)acol[e];
      if (c == s0 || c == s1) {
        const float v = avalS[e];
        const float v0 = (c == s0) ? v : 0.f;
        const float v1 = (c == s1) ? v : 0.f;
        const int r = (int)arow[e];
#pragma unroll
        for (int slot = 0; slot < MAXP; slot++)
          if (cnt == slot) { gi[slot] = r; gv0[slot] = v0; gv1[slot] = v1; }
        cnt++;
      }
    }
  }
  const float p0 = (tid < 54) ? pi_lds[2 * tid] : 0.f;
  const float p1 = (tid < 54) ? pi_lds[2 * tid + 1] : 0.f;
  __syncthreads();   // Bt_lds + avalS consumption done

  // ---------- phase 4: un-normalized forward scan, NO barriers in the loop ----------
  // Single wave: intra-wave LDS write->read ordering is maintained by the
  // in-order DS pipe; the compiler inserts minimal lgkmcnt waits for the
  // register data deps. Global stores stay in flight (no vmcnt drain).
  const int* seq = inp + (size_t)blockIdx.x * T_LEN;
  float* ob = out + (size_t)blockIdx.x * T_LEN * S;
  const int l2 = 2 * tid;

  int e0 = seq[0];
  float u0 = 0.f, u1 = 0.f;
  if (tid < 54) {
    u0 = p0 * Bt_lds[e0 * S + l2];
    u1 = p1 * Bt_lds[e0 * S + l2 + 1];
    *(float2*)&ob[l2] = make_float2(u0, u1);
  }
  *(float2*)&alpha_lds[l2] = make_float2(u0, u1);   // lanes>=54 write pad slots (0)
  __syncthreads();   // once, before the loop

  int etn = seq[1];
  for (int t = 1; t < T_LEN; t++) {
    const int ecur = etn;
    if (t + 1 < T_LEN) etn = seq[t + 1];   // uniform prefetch, covered 1 iter ahead
    const float2 bt = *(const float2*)&Bt_lds[ecur * S + l2];  // independent of alpha
    float a0 = 0.f, a1 = 0.f, b0 = 0.f, b1 = 0.f;
#pragma unroll
    for (int e = 0; e < MAXP; e += 2) {
      const float x = alpha_lds[gi[e]];
      const float y = alpha_lds[gi[e + 1]];
      a0 += x * gv0[e];     b0 += x * gv1[e];
      a1 += y * gv0[e + 1]; b1 += y * gv1[e + 1];
    }
    u0 = (a0 + a1) * bt.x;
    u1 = (b0 + b1) * bt.y;

    if ((t & 15) == 15) {                  // periodic rescale against underflow
      float m = fmaxf(u0, u1);
#pragma unroll
      for (int msk = 1; msk < 64; msk <<= 1) m = fmaxf(m, __shfl_xor(m, msk, 64));
      const float r = 1.f / m;
      u0 *= r; u1 *= r;
    }

    *(float2*)&alpha_lds[l2] = make_float2(u0, u1);
    if (tid < 54) *(float2*)&ob[(size_t)t * S + l2] = make_float2(u0, u1);
    // no __syncthreads: keeps the global store off the critical path
  }
}

// ---------- kernel 2: per-row normalization, fully parallel, BW-bound ----------
__global__ __launch_bounds__(256, 8) void hmm_norm_kernel(float* __restrict__ out,
                                                          int nrows) {
  const int wid = (int)((blockIdx.x * 256u + threadIdx.x) >> 6);  // one wave per row
  const int l = threadIdx.x & 63;
  if (wid >= nrows) return;
  float* row = out + (size_t)wid * S;
  float2 x = make_float2(0.f, 0.f);
  if (l < 54) x = *(const float2*)&row[2 * l];
  float s = x.x + x.y;
#pragma unroll
  for (int msk = 1; msk < 64; msk <<= 1) s += __shfl_xor(s, msk, 64);
  const float inv = 1.f / s;
  if (l < 54) *(float2*)&row[2 * l] = make_float2(x.x * inv, x.y * inv);
}

extern "C" void kernel_launch(void* const* d_in, const int* in_sizes, int n_in,
                              void* d_out, int out_size, void* d_ws, size_t ws_size,
                              hipStream_t stream) {
  const int* inp = (const int*)d_in[0];        // [256, 2048] int32 kmer ids
  const float* w = (const float*)d_in[1];      // transition_kernel [53]
  const float* ek = (const float*)d_in[2];     // emission_kernel [108*216]
  const float* ik = (const float*)d_in[3];     // init_kernel [108]
  float* out = (float*)d_out;                  // [256, 2048, 108] f32
  (void)d_ws; (void)ws_size; (void)in_sizes; (void)n_in; (void)out_size;
  hmm_scan_kernel<<<N_BATCH, 64, 0, stream>>>(inp, w, ek, ik, out);
  const int nrows = N_BATCH * T_LEN;           // 524288 rows
  hmm_norm_kernel<<<nrows / 4, 256, 0, stream>>>(out, nrows);
}

// Round 4
// 1176.050 us; speedup vs baseline: 2.2296x; 2.2296x over previous
//
#include <hip/hip_runtime.h>
#include <cstdint>
#include <cstddef>

#define S 108
#define NEMIT 126
#define NCOD 16
#define T_LEN 2048
#define N_BATCH 256
#define MAXP 20    // max in-degree of column pair (2l,2l+1) of A is 19
#define MAXNE 6500 // emission nnz upper bound (actual 6432)

// ================= compile-time emission structure =================
// Mirrors _emission_structure(16): (row, col, widx) triples in exact
// Python product() order, plus row_ptr (rows are emitted non-decreasing).
struct EmTab {
  short row[MAXNE];
  short col[MAXNE];
  short widx[MAXNE];
  int rp[S + 1];
  int n;
  int nw;
};

constexpr int cmask(int sym, int add4) {
  int m = (sym == 4) ? 0xF : (1 << sym);
  if (add4) m |= 0x10;
  return m;
}

constexpr EmTab buildEm() {
  EmTab E{};
  int n = 0, k = 0;
  auto doCall = [&](int stt, int s0_, int s1_, int s2_, int xm_, int tr_) {
    const int m0 = cmask(s0_, xm_ < 2 ? 1 : 0);
    const int m1 = cmask(s1_, xm_ < 1 ? 1 : 0);
    const int m2 = cmask(s2_, 0);
    for (int x0 = 0; x0 < 5; x0++) {
      if (!((m0 >> x0) & 1)) continue;
      for (int x1 = 0; x1 < 5; x1++) {
        if (!((m1 >> x1) & 1)) continue;
        if (x0 != 4 && x1 == 4) continue;   // pads only as prefix of first two
        for (int x2 = 0; x2 < 5; x2++) {
          if (!((m2 >> x2) & 1)) continue;
          E.row[n] = (short)stt;
          E.col[n] = (short)(x0 * 25 + x1 * 5 + x2);
          E.widx[n] = (short)(tr_ ? k++ : -1);
          n++;
        }
      }
    }
  };
  doCall(0, 4, 4, 4, 0, 1);            // 'N'
  doCall(1, 4, 4, 0, 0, 1);            // 'A'
  doCall(2, 4, 0, 3, 0, 1);            // 'AT'
  doCall(3, 0, 3, 2, 2, 0);            // 'ATG' (non-trainable)
  doCall(4, 3, 2, 4, 2, 1);            // 'ATGN'
  doCall(5, 2, 4, 4, 2, 1);            // 'ATGNN'
  for (int s = 6; s <= 51; s++) doCall(s, 4, 4, 4, 2, 1);
  doCall(52, 4, 4, 3, 2, 1);           // 'T'
  doCall(53, 4, 3, 0, 2, 1);           // 'TA'
  doCall(53, 4, 3, 2, 2, 1);           // 'TG'
  doCall(54, 3, 0, 0, 2, 0);           // 'TAA'
  doCall(54, 3, 0, 2, 2, 0);           // 'TAG'
  doCall(54, 3, 2, 0, 2, 0);           // 'TGA'
  doCall(55, 4, 4, 4, 2, 1);
  for (int s = 56; s <= 106; s++) doCall(s, 4, 4, 4, 2, 1);
  E.row[n] = 107; E.col[n] = 125; E.widx[n] = -1; n++;   // 'X'
  E.n = n; E.nw = k;
  for (int r = 0; r <= S; r++) E.rp[r] = 0;
  for (int e = 0; e < n; e++) E.rp[E.row[e] + 1]++;
  for (int r = 0; r < S; r++) E.rp[r + 1] += E.rp[r];
  return E;
}

constexpr EmTab EM_HOST = buildEm();
static_assert(EM_HOST.n <= MAXNE && EM_HOST.n > 6000, "emission count sanity");
static_assert(EM_HOST.nw <= S * 216, "weight count sanity");
__device__ const EmTab g_em = EM_HOST;

// ================= the fused kernel =================
__global__ __launch_bounds__(64, 1) void hmm_scan_kernel(
    const int* __restrict__ inp, const float* __restrict__ w,
    const float* __restrict__ ek, const float* __restrict__ ik,
    float* __restrict__ out) {
  __shared__ __align__(16) float Bt_lds[NEMIT * S];  // Bt[col*S + state], 54.4 KB
  __shared__ __align__(8) float alpha_lds[128];
  __shared__ float pi_lds[S];
  __shared__ short arow[288], acol[288];
  __shared__ float avalS[288];
  __shared__ int s_ne;

  const int tid = threadIdx.x;   // 64 threads = 1 wave

  // ---------- phase 0: zero Bt; pi via wave shuffles; A entries (lane 1) ----------
  for (int i = tid; i < NEMIT * S; i += 64) Bt_lds[i] = 0.f;

  {  // pi = softmax(ik), parallel
    float q0 = (tid < S) ? ik[tid] : -1e30f;
    float q1 = (tid + 64 < S) ? ik[tid + 64] : -1e30f;
    float mx = fmaxf(q0, q1);
#pragma unroll
    for (int msk = 1; msk < 64; msk <<= 1) mx = fmaxf(mx, __shfl_xor(mx, msk, 64));
    float e0 = (tid < S) ? expf(q0 - mx) : 0.f;
    float e1 = (tid + 64 < S) ? expf(q1 - mx) : 0.f;
    float zz = e0 + e1;
#pragma unroll
    for (int msk = 1; msk < 64; msk <<= 1) zz += __shfl_xor(zz, msk, 64);
    const float rz = 1.f / zz;
    if (tid < S) pi_lds[tid] = e0 * rz;
    if (tid + 64 < S) pi_lds[tid + 64] = e1 * rz;
  }

  if (tid == 1) {
    // _build_A(w, 16) entry list (280 entries)
    int ne = 0;
    auto AD = [&](int r, int c2, float v) {
      arow[ne] = (short)r; acol[ne] = (short)c2; avalS[ne] = v; ne++;
    };
    float w0 = w[0];
    AD(0, 0, 1.f - w0); AD(0, 1, w0); AD(1, 2, 1.f); AD(2, 3, 1.f);
    int k = 1;
    for (int i = 0; i < NCOD; i++) AD(3 + 3 * i, 4 + 3 * i, w[k + i]);
    k += NCOD;                                            // k = 17
    for (int i = 0; i < NCOD; i++) AD(4 + 3 * i, 5 + 3 * i, 1.f);
    for (int i = 0; i < NCOD; i++) AD(5 + 3 * i, 6 + 3 * i, 1.f);
    for (int i = 0; i <= NCOD; i++) AD(3 + 3 * i, 56 + 3 * i, w[k + i]);
    k += NCOD + 1;                                        // k = 34
    AD(51, 52, w[k]); k += 1;                             // k = 35
    for (int i = 0; i <= NCOD; i++) AD(56 + 3 * i, 57 + 3 * i, 1.f);
    for (int i = 0; i <= NCOD; i++) AD(57 + 3 * i, 58 + 3 * i, 1.f);
    for (int i = 0; i <= NCOD; i++) AD(58 + 3 * i, 4 + 3 * i, w[k + i]);
    for (int i = 0; i <= NCOD; i++) AD(58 + 3 * i, 56 + 3 * i, 1.f - w[k + i]);
    k += NCOD + 1;                                        // k = 52
    const float wk = w[k];
    const float sgnw = (wk > 0.f) ? 1.f : ((wk < 0.f) ? -1.f : 0.f);
    const float aw = fabsf(wk);
    for (int a = 0; a < NCOD; a++) {
      float pw = aw * aw;                                 // |wk|^2 at jj=a+1
      int e = 2;
      for (int jj = a + 1; jj <= NCOD; jj++) {
        const float sgn = (e & 1) ? sgnw : 1.f;
        AD(3 + 3 * a, 4 + 3 * jj, 1.f - sgn * pw);
        pw *= aw; e++;
      }
    }
    AD(52, 53, 1.f); AD(53, 54, 1.f); AD(54, 55, 1.f);
    AD(55, 55, 1.f); AD(55, 107, 1.f); AD(107, 107, 1.f);
    s_ne = ne;                                            // = 280
  }
  __syncthreads();

  const int ne = s_ne;

  // ---------- phase 1a: A row-softmax (in-place on avalS; disjoint rows/lane) ----
  for (int s = tid; s < S; s += 64) {
    float m = -1e30f;
    for (int e = 0; e < ne; e++)
      if (arow[e] == s) m = fmaxf(m, avalS[e]);
    float z = 0.f;
    for (int e = 0; e < ne; e++)
      if (arow[e] == s) z += expf(avalS[e] - m);
    const float rz = 1.f / z;
    for (int e = 0; e < ne; e++)
      if (arow[e] == s) avalS[e] = expf(avalS[e] - m) * rz;
  }

  // ---------- phase 1b: B row-softmax from compile-time table (parallel) --------
#pragma unroll
  for (int rr = 0; rr < 2; rr++) {
    const int r = tid + rr * 64;
    if (r < S) {
      const int b = g_em.rp[r], e2 = g_em.rp[r + 1];
      float m = -1e30f;
      for (int e = b; e < e2; e++) {
        const int wi = g_em.widx[e];
        const float v = (wi >= 0) ? ek[wi] : 1.f;
        m = fmaxf(m, v);
      }
      float z = 0.f;
      for (int e = b; e < e2; e++) {
        const int wi = g_em.widx[e];
        const float v = (wi >= 0) ? ek[wi] : 1.f;
        z += expf(v - m);
      }
      const float rz = 1.f / z;
      for (int e = b; e < e2; e++) {
        const int wi = g_em.widx[e];
        const float v = (wi >= 0) ? ek[wi] : 1.f;
        Bt_lds[(int)g_em.col[e] * S + r] = expf(v - m) * rz;
      }
    }
  }
  __syncthreads();   // avalS final, Bt_lds final

  // ---------- phase 2: per-lane CSC of A columns (2l, 2l+1), static slots -------
  const int s0 = (tid < 54) ? 2 * tid : -1;
  const int s1 = (tid < 54) ? 2 * tid + 1 : -1;
  float gv0[MAXP], gv1[MAXP];
  int gi[MAXP];
#pragma unroll
  for (int e = 0; e < MAXP; e++) { gv0[e] = 0.f; gv1[e] = 0.f; gi[e] = 0; }
  {
    int cnt = 0;
    for (int e = 0; e < ne; e++) {
      const int c = (int)acol[e];
      if (c == s0 || c == s1) {
        const float v = avalS[e];
        const float v0 = (c == s0) ? v : 0.f;
        const float v1 = (c == s1) ? v : 0.f;
        const int r = (int)arow[e];
#pragma unroll
        for (int slot = 0; slot < MAXP; slot++)
          if (cnt == slot) { gi[slot] = r; gv0[slot] = v0; gv1[slot] = v1; }
        cnt++;
      }
    }
  }
  const float p0 = (tid < 54) ? pi_lds[2 * tid] : 0.f;
  const float p1 = (tid < 54) ? pi_lds[2 * tid + 1] : 0.f;
  __syncthreads();

  // ---------- phase 3: forward scan, fused normalization, no in-loop barriers ---
  const int* seq = inp + (size_t)blockIdx.x * T_LEN;
  float* ob = out + (size_t)blockIdx.x * T_LEN * S;
  const int l2 = 2 * tid;

  const int e0 = seq[0];
  float u0 = 0.f, u1 = 0.f;
  if (tid < 54) {
    u0 = p0 * Bt_lds[e0 * S + l2];
    u1 = p1 * Bt_lds[e0 * S + l2 + 1];
  }
  *(float2*)&alpha_lds[l2] = make_float2(u0, u1);
  {
    float ssum = u0 + u1;
#pragma unroll
    for (int msk = 1; msk < 64; msk <<= 1) ssum += __shfl_xor(ssum, msk, 64);
    const float inv = 1.f / ssum;
    if (tid < 54) *(float2*)&ob[l2] = make_float2(u0 * inv, u1 * inv);
  }
  __syncthreads();   // once, before the loop

  int etn = seq[1];
  for (int t = 1; t < T_LEN; t++) {
    const int ecur = etn;
    if (t + 1 < T_LEN) etn = seq[t + 1];   // uniform prefetch, covered 1 iter ahead
    const float2 bt = *(const float2*)&Bt_lds[ecur * S + l2];
    float a0 = 0.f, a1 = 0.f, b0 = 0.f, b1 = 0.f;
#pragma unroll
    for (int e = 0; e < MAXP; e += 2) {
      const float x = alpha_lds[gi[e]];
      const float y = alpha_lds[gi[e + 1]];
      a0 += x * gv0[e];     b0 += x * gv1[e];
      a1 += y * gv0[e + 1]; b1 += y * gv1[e + 1];
    }
    u0 = (a0 + a1) * bt.x;
    u1 = (b0 + b1) * bt.y;

    if ((t & 15) == 15) {                  // periodic rescale against underflow
      float m = fmaxf(u0, u1);
#pragma unroll
      for (int msk = 1; msk < 64; msk <<= 1) m = fmaxf(m, __shfl_xor(m, msk, 64));
      const float r = 1.f / m;
      u0 *= r; u1 *= r;
    }

    *(float2*)&alpha_lds[l2] = make_float2(u0, u1);   // critical-path write first

    // fused per-step normalization: shuffle-sum + store run while the next
    // iteration's DS gathers are already behind them in the in-order pipe.
    float ssum = u0 + u1;
#pragma unroll
    for (int msk = 1; msk < 64; msk <<= 1) ssum += __shfl_xor(ssum, msk, 64);
    const float inv = 1.f / ssum;
    if (tid < 54) *(float2*)&ob[(size_t)t * S + l2] = make_float2(u0 * inv, u1 * inv);
  }
}

extern "C" void kernel_launch(void* const* d_in, const int* in_sizes, int n_in,
                              void* d_out, int out_size, void* d_ws, size_t ws_size,
                              hipStream_t stream) {
  const int* inp = (const int*)d_in[0];        // [256, 2048] int32 kmer ids
  const float* w = (const float*)d_in[1];      // transition_kernel [53]
  const float* ek = (const float*)d_in[2];     // emission_kernel [108*216]
  const float* ik = (const float*)d_in[3];     // init_kernel [108]
  float* out = (float*)d_out;                  // [256, 2048, 108] f32
  (void)d_ws; (void)ws_size; (void)in_sizes; (void)n_in; (void)out_size;
  hmm_scan_kernel<<<N_BATCH, 64, 0, stream>>>(inp, w, ek, ik, out);
}

// Round 5
// 927.187 us; speedup vs baseline: 2.8281x; 1.2684x over previous
//
#include <hip/hip_runtime.h>
#include <cstdint>
#include <cstddef>

#define S 108
#define NEMIT 126
#define NCOD 16
#define T_LEN 2048
#define N_BATCH 256
#define MAXG 12    // max gather entries per lane after balancing
#define MAXNE 6500 // emission nnz upper bound (actual 6432)

// ================= compile-time emission structure =================
struct EmTab {
  short row[MAXNE];
  short col[MAXNE];
  short widx[MAXNE];
  int rp[S + 1];
  int n;
  int nw;
};

constexpr int cmask(int sym, int add4) {
  int m = (sym == 4) ? 0xF : (1 << sym);
  if (add4) m |= 0x10;
  return m;
}

constexpr EmTab buildEm() {
  EmTab E{};
  int n = 0, k = 0;
  auto doCall = [&](int stt, int s0_, int s1_, int s2_, int xm_, int tr_) {
    const int m0 = cmask(s0_, xm_ < 2 ? 1 : 0);
    const int m1 = cmask(s1_, xm_ < 1 ? 1 : 0);
    const int m2 = cmask(s2_, 0);
    for (int x0 = 0; x0 < 5; x0++) {
      if (!((m0 >> x0) & 1)) continue;
      for (int x1 = 0; x1 < 5; x1++) {
        if (!((m1 >> x1) & 1)) continue;
        if (x0 != 4 && x1 == 4) continue;
        for (int x2 = 0; x2 < 5; x2++) {
          if (!((m2 >> x2) & 1)) continue;
          E.row[n] = (short)stt;
          E.col[n] = (short)(x0 * 25 + x1 * 5 + x2);
          E.widx[n] = (short)(tr_ ? k++ : -1);
          n++;
        }
      }
    }
  };
  doCall(0, 4, 4, 4, 0, 1);
  doCall(1, 4, 4, 0, 0, 1);
  doCall(2, 4, 0, 3, 0, 1);
  doCall(3, 0, 3, 2, 2, 0);
  doCall(4, 3, 2, 4, 2, 1);
  doCall(5, 2, 4, 4, 2, 1);
  for (int s = 6; s <= 51; s++) doCall(s, 4, 4, 4, 2, 1);
  doCall(52, 4, 4, 3, 2, 1);
  doCall(53, 4, 3, 0, 2, 1);
  doCall(53, 4, 3, 2, 2, 1);
  doCall(54, 3, 0, 0, 2, 0);
  doCall(54, 3, 0, 2, 2, 0);
  doCall(54, 3, 2, 0, 2, 0);
  doCall(55, 4, 4, 4, 2, 1);
  for (int s = 56; s <= 106; s++) doCall(s, 4, 4, 4, 2, 1);
  E.row[n] = 107; E.col[n] = 125; E.widx[n] = -1; n++;
  E.n = n; E.nw = k;
  for (int r = 0; r <= S; r++) E.rp[r] = 0;
  for (int e = 0; e < n; e++) E.rp[E.row[e] + 1]++;
  for (int r = 0; r < S; r++) E.rp[r + 1] += E.rp[r];
  return E;
}

constexpr EmTab EM_HOST = buildEm();
static_assert(EM_HOST.n <= MAXNE && EM_HOST.n > 6000, "emission count sanity");
__device__ const EmTab g_em = EM_HOST;

// ================= scan kernel =================
__global__ __launch_bounds__(64, 1) void hmm_scan_kernel(
    const int* __restrict__ inp, const float* __restrict__ w,
    const float* __restrict__ ek, const float* __restrict__ ik,
    float* __restrict__ out) {
  __shared__ __align__(16) float Bt_lds[NEMIT * S];
  __shared__ float alpha_lds[128];     // 108 states + 14 piece pads + trash(127)
  __shared__ float pi_lds[S];
  __shared__ short arow[280], acol[280];
  __shared__ float avalS[280];
  __shared__ int s_ne;
  // planner state
  __shared__ short ccnt[S];
  __shared__ short clist[S][18];
  __shared__ short npcA[S];
  __shared__ short pdefs[16][6];
  __shared__ short pcnt_s[16], pcol_s[16];
  // per-lane plan
  __shared__ unsigned char p_src[64][MAXG];
  __shared__ short p_a0[64][MAXG], p_a1[64][MAXG];
  __shared__ unsigned char p_dslot[64][2], p_btc[64][2];
  __shared__ short p_outc[64][2];
  __shared__ short p_scol[64];
  __shared__ unsigned char p_sm1[64], p_sm2[64];
  __shared__ unsigned char lload[64], lnit[64];

  const int tid = threadIdx.x;   // 64 threads = 1 wave

  // ---------- phase 0: zero Bt; plan defaults; pi softmax; A entries ----------
  for (int i = tid; i < NEMIT * S; i += 64) Bt_lds[i] = 0.f;
#pragma unroll
  for (int e = 0; e < MAXG; e++) {
    p_src[tid][e] = 0; p_a0[tid][e] = -1; p_a1[tid][e] = -1;
  }
  p_dslot[tid][0] = 127; p_dslot[tid][1] = 127;
  p_btc[tid][0] = 0; p_btc[tid][1] = 0;
  p_outc[tid][0] = -1; p_outc[tid][1] = -1;
  p_scol[tid] = -1; p_sm1[tid] = 0; p_sm2[tid] = 0;
  lload[tid] = 0; lnit[tid] = 0;

  {  // pi = softmax(ik)
    float q0 = (tid < S) ? ik[tid] : -1e30f;
    float q1 = (tid + 64 < S) ? ik[tid + 64] : -1e30f;
    float mx = fmaxf(q0, q1);
#pragma unroll
    for (int msk = 1; msk < 64; msk <<= 1) mx = fmaxf(mx, __shfl_xor(mx, msk, 64));
    float e0v = (tid < S) ? expf(q0 - mx) : 0.f;
    float e1v = (tid + 64 < S) ? expf(q1 - mx) : 0.f;
    float zz = e0v + e1v;
#pragma unroll
    for (int msk = 1; msk < 64; msk <<= 1) zz += __shfl_xor(zz, msk, 64);
    const float rz = 1.f / zz;
    if (tid < S) pi_lds[tid] = e0v * rz;
    if (tid + 64 < S) pi_lds[tid + 64] = e1v * rz;
  }

  if (tid == 1) {
    // _build_A(w, 16): 280 entries
    int ne = 0;
    auto AD = [&](int r, int c2, float v) {
      arow[ne] = (short)r; acol[ne] = (short)c2; avalS[ne] = v; ne++;
    };
    float w0 = w[0];
    AD(0, 0, 1.f - w0); AD(0, 1, w0); AD(1, 2, 1.f); AD(2, 3, 1.f);
    int k = 1;
    for (int i = 0; i < NCOD; i++) AD(3 + 3 * i, 4 + 3 * i, w[k + i]);
    k += NCOD;
    for (int i = 0; i < NCOD; i++) AD(4 + 3 * i, 5 + 3 * i, 1.f);
    for (int i = 0; i < NCOD; i++) AD(5 + 3 * i, 6 + 3 * i, 1.f);
    for (int i = 0; i <= NCOD; i++) AD(3 + 3 * i, 56 + 3 * i, w[k + i]);
    k += NCOD + 1;
    AD(51, 52, w[k]); k += 1;
    for (int i = 0; i <= NCOD; i++) AD(56 + 3 * i, 57 + 3 * i, 1.f);
    for (int i = 0; i <= NCOD; i++) AD(57 + 3 * i, 58 + 3 * i, 1.f);
    for (int i = 0; i <= NCOD; i++) AD(58 + 3 * i, 4 + 3 * i, w[k + i]);
    for (int i = 0; i <= NCOD; i++) AD(58 + 3 * i, 56 + 3 * i, 1.f - w[k + i]);
    k += NCOD + 1;
    const float wk = w[k];
    const float sgnw = (wk > 0.f) ? 1.f : ((wk < 0.f) ? -1.f : 0.f);
    const float aw = fabsf(wk);
    for (int a = 0; a < NCOD; a++) {
      float pw = aw * aw;
      int e = 2;
      for (int jj = a + 1; jj <= NCOD; jj++) {
        const float sgn = (e & 1) ? sgnw : 1.f;
        AD(3 + 3 * a, 4 + 3 * jj, 1.f - sgn * pw);
        pw *= aw; e++;
      }
    }
    AD(52, 53, 1.f); AD(53, 54, 1.f); AD(54, 55, 1.f);
    AD(55, 55, 1.f); AD(55, 107, 1.f); AD(107, 107, 1.f);
    s_ne = ne;    // = 280
  }
  __syncthreads();

  const int ne = s_ne;

  // ---------- phase 1: A row-softmax (parallel) + per-col source lists ----------
  for (int s = tid; s < S; s += 64) {
    float m = -1e30f;
    for (int e = 0; e < ne; e++)
      if (arow[e] == s) m = fmaxf(m, avalS[e]);
    float z = 0.f;
    for (int e = 0; e < ne; e++)
      if (arow[e] == s) z += expf(avalS[e] - m);
    const float rz = 1.f / z;
    for (int e = 0; e < ne; e++)
      if (arow[e] == s) avalS[e] = expf(avalS[e] - m) * rz;
  }
  for (int c = tid; c < S; c += 64) {
    int cnt = 0;
    for (int e = 0; e < ne; e++)
      if (acol[e] == c) { clist[c][cnt] = (short)e; cnt++; }
    ccnt[c] = (short)cnt;
  }
  __syncthreads();

  // ---------- phase 2: B row-softmax (parallel) + planner (lane 0) ----------
#pragma unroll
  for (int rr2 = 0; rr2 < 2; rr2++) {
    const int r = tid + rr2 * 64;
    if (r < S) {
      const int b = g_em.rp[r], e2 = g_em.rp[r + 1];
      float m = -1e30f;
      for (int e = b; e < e2; e++) {
        const int wi = g_em.widx[e];
        m = fmaxf(m, (wi >= 0) ? ek[wi] : 1.f);
      }
      float z = 0.f;
      for (int e = b; e < e2; e++) {
        const int wi = g_em.widx[e];
        z += expf(((wi >= 0) ? ek[wi] : 1.f) - m);
      }
      const float rz = 1.f / z;
      for (int e = b; e < e2; e++) {
        const int wi = g_em.widx[e];
        Bt_lds[(int)g_em.col[e] * S + r] = expf(((wi >= 0) ? ek[wi] : 1.f) - m) * rz;
      }
    }
  }

  if (tid == 0) {
    // --- decomposition: carve heavy columns into pieces of 6 sources ---
    int np = 0;
    for (int c = 0; c < S; c++) npcA[c] = 0;
    for (int c = 0; c < S; c++) {
      while (ccnt[c] > 8) {
        const int base = ccnt[c] - 6;
        for (int j = 0; j < 6; j++) pdefs[np][j] = clist[c][base + j];
        pcnt_s[np] = 6; pcol_s[np] = (short)c;
        npcA[c]++; ccnt[c] = (short)(ccnt[c] - 6); np++;
      }
    }
    // --- consumers (unique readers of split cols) -> lanes 54..63, item0 ---
    int ncons = 0;
    for (int c = 0; c < S; c++) {
      if (ccnt[c] == 1) {
        const int e0 = clist[c][0];
        const int r = arow[e0];
        if (npcA[r] > 0) {
          const int l = 54 + ncons; ncons++;
          int k = 0;
          p_src[l][k] = (unsigned char)r; p_a0[l][k] = (short)e0; k++;
          for (int p = 0; p < np; p++)
            if (pcol_s[p] == r) {
              p_src[l][k] = (unsigned char)(108 + p); p_a0[l][k] = (short)e0; k++;
            }
          p_dslot[l][0] = (unsigned char)c; p_btc[l][0] = (unsigned char)c;
          p_outc[l][0] = (short)c;
          p_scol[l] = (short)r;
          p_sm1[l] = (k >= 2) ? 1 : 0; p_sm2[l] = (k >= 3) ? 1 : 0;
          lload[l] = (unsigned char)k; lnit[l] = 1;
          ccnt[c] = 0;   // consumed
        }
      }
    }
    // --- snake-deal remaining items (pieces + real cols), big first ---
    int rr = 0;
    auto pickLane = [&](int L) {
      for (;;) {
        const int pos = rr & 127; rr++;
        const int l = (pos < 64) ? pos : (127 - pos);
        if (lnit[l] < 2 && (int)lload[l] + L <= MAXG) return l;
      }
    };
    for (int th = 8; th >= 1; th--) {
      for (int p = 0; p < np; p++) {
        if ((int)pcnt_s[p] != th) continue;
        const int l = pickLane(th);
        const int it = lnit[l]; const int base = lload[l];
        for (int j = 0; j < th; j++) {
          p_src[l][base + j] = (unsigned char)arow[pdefs[p][j]];
          if (it == 0) p_a0[l][base + j] = pdefs[p][j];
          else         p_a1[l][base + j] = pdefs[p][j];
        }
        p_dslot[l][it] = (unsigned char)(108 + p);
        p_btc[l][it] = (unsigned char)pcol_s[p];
        p_outc[l][it] = -1;
        lload[l] = (unsigned char)(base + th); lnit[l] = (unsigned char)(it + 1);
      }
      for (int c = 0; c < S; c++) {
        if ((int)ccnt[c] != th) continue;
        const int l = pickLane(th);
        const int it = lnit[l]; const int base = lload[l];
        for (int j = 0; j < th; j++) {
          p_src[l][base + j] = (unsigned char)arow[clist[c][j]];
          if (it == 0) p_a0[l][base + j] = clist[c][j];
          else         p_a1[l][base + j] = clist[c][j];
        }
        p_dslot[l][it] = (unsigned char)c;
        p_btc[l][it] = (unsigned char)c;
        p_outc[l][it] = (npcA[c] > 0) ? (short)-1 : (short)c;
        lload[l] = (unsigned char)(base + th); lnit[l] = (unsigned char)(it + 1);
      }
    }
  }
  __syncthreads();

  // ---------- phase 3: load per-lane plan into registers ----------
  int gsrc[MAXG]; float w0v[MAXG], w1v[MAXG];
#pragma unroll
  for (int e = 0; e < MAXG; e++) {
    gsrc[e] = p_src[tid][e];
    const int a0 = p_a0[tid][e], a1 = p_a1[tid][e];
    w0v[e] = (a0 >= 0) ? avalS[a0] : 0.f;
    w1v[e] = (a1 >= 0) ? avalS[a1] : 0.f;
  }
  const int d0 = p_dslot[tid][0], d1 = p_dslot[tid][1];
  const int b0c = p_btc[tid][0], b1c = p_btc[tid][1];
  const int o0 = p_outc[tid][0], o1 = p_outc[tid][1];
  const int scol = p_scol[tid];
  const float sm1 = (float)p_sm1[tid], sm2 = (float)p_sm2[tid];
  __syncthreads();

  // ---------- phase 4: forward scan (unnormalized), no in-loop cross-lane ------
  const int* seq = inp + (size_t)blockIdx.x * T_LEN;
  float* ob = out + (size_t)blockIdx.x * T_LEN * S;

  const int e0s = seq[0];
  {
    const float ui0 = (d0 < 108) ? pi_lds[d0] * Bt_lds[e0s * S + d0] : 0.f;
    const float ui1 = (d1 < 108) ? pi_lds[d1] * Bt_lds[e0s * S + d1] : 0.f;
    alpha_lds[d0] = ui0;
    alpha_lds[d1] = ui1;
  }
  __syncthreads();
  for (int i = tid; i < S; i += 64) ob[i] = alpha_lds[i];   // row 0 (unnormalized)

  int etn = seq[1];
  for (int t = 1; t < T_LEN; t++) {
    const int ecur = etn;
    if (t + 1 < T_LEN) etn = seq[t + 1];
    const float bt0 = Bt_lds[ecur * S + b0c];   // issue early, overlaps gathers
    const float bt1 = Bt_lds[ecur * S + b1c];
    float x[MAXG];
#pragma unroll
    for (int e = 0; e < MAXG; e++) x[e] = alpha_lds[gsrc[e]];
    float aA = 0.f, aB = 0.f, bA = 0.f, bB = 0.f;
#pragma unroll
    for (int e = 0; e < MAXG; e += 2) {
      aA += x[e] * w0v[e];     aB += x[e + 1] * w0v[e + 1];
      bA += x[e] * w1v[e];     bB += x[e + 1] * w1v[e + 1];
    }
    float u0 = (aA + aB) * bt0;
    float u1 = (bA + bB) * bt1;
    const float sumv = x[0] + sm1 * x[1] + sm2 * x[2];   // consumer: full split-col value (row t-1)

    if ((t & 15) == 15) {                  // periodic wave-uniform rescale
      float m = fmaxf(u0, u1);
#pragma unroll
      for (int msk = 1; msk < 64; msk <<= 1) m = fmaxf(m, __shfl_xor(m, msk, 64));
      const float r = 1.f / m;
      u0 *= r; u1 *= r;
    }

    alpha_lds[d0] = u0;
    alpha_lds[d1] = u1;
    if (o0 >= 0) ob[(size_t)t * S + o0] = u0;
    if (o1 >= 0) ob[(size_t)t * S + o1] = u1;
    if (scol >= 0) ob[(size_t)(t - 1) * S + scol] = sumv;
  }
  // epilogue: last row's split-col values
  if (scol >= 0) {
    const float x0 = alpha_lds[gsrc[0]];
    const float x1 = alpha_lds[gsrc[1]];
    const float x2 = alpha_lds[gsrc[2]];
    ob[(size_t)(T_LEN - 1) * S + scol] = x0 + sm1 * x1 + sm2 * x2;
  }
}

// ---------- kernel 2: per-row normalization, fully parallel, BW-bound ----------
__global__ __launch_bounds__(256, 8) void hmm_norm_kernel(float* __restrict__ out,
                                                          int nrows) {
  const int wid = (int)((blockIdx.x * 256u + threadIdx.x) >> 6);  // one wave per row
  const int l = threadIdx.x & 63;
  if (wid >= nrows) return;
  float* row = out + (size_t)wid * S;
  float2 x = make_float2(0.f, 0.f);
  if (l < 54) x = *(const float2*)&row[2 * l];
  float s = x.x + x.y;
#pragma unroll
  for (int msk = 1; msk < 64; msk <<= 1) s += __shfl_xor(s, msk, 64);
  const float inv = 1.f / s;
  if (l < 54) *(float2*)&row[2 * l] = make_float2(x.x * inv, x.y * inv);
}

extern "C" void kernel_launch(void* const* d_in, const int* in_sizes, int n_in,
                              void* d_out, int out_size, void* d_ws, size_t ws_size,
                              hipStream_t stream) {
  const int* inp = (const int*)d_in[0];
  const float* w = (const float*)d_in[1];
  const float* ek = (const float*)d_in[2];
  const float* ik = (const float*)d_in[3];
  float* out = (float*)d_out;
  (void)d_ws; (void)ws_size; (void)in_sizes; (void)n_in; (void)out_size;
  hmm_scan_kernel<<<N_BATCH, 64, 0, stream>>>(inp, w, ek, ik, out);
  const int nrows = N_BATCH * T_LEN;
  hmm_norm_kernel<<<nrows / 4, 256, 0, stream>>>(out, nrows);
}